// Round 8
// baseline (760.454 us; speedup 1.0000x reference)
//
#include <hip/hip_runtime.h>
#include <hip/hip_bf16.h>

#define NROWS 16384
#define HDIM  2048
#define HHALF 1024
#define NC    32
#define REFINE_TH 0.012f
#define REFINE_CAP 16384

typedef __attribute__((ext_vector_type(8)))  short  short8;
typedef __attribute__((ext_vector_type(16))) float  f32x16;

typedef __attribute__((address_space(3))) void lds_void;
typedef const __attribute__((address_space(1))) void gbl_void;

static __device__ __forceinline__ short f2h(float f) {
    _Float16 h = (_Float16)f;
    return *(short*)&h;
}
static __device__ __forceinline__ void gload16(const void* g, void* l) {
    __builtin_amdgcn_global_load_lds((gbl_void*)g, (lds_void*)l, 16, 0, 0);
}

// ---------------------------------------------------------------------------
// ws: [0,64K) idx | [64K,+128) counts | [128K,384K) kcent | [384K,640K) vcent
// [640K,896K) hk | [896K,1152K) hv | [1152K,1408K) tck | [1408K,1664K) tcv
//
// d_out (256MiB) = scratch until k_out overwrites it:
// [0,64M) kh (fp16 keys) | [128M,160M) hidH (fp16) | [192M,196M) w1h |
// [200M,+64K) w2h | [201M,+2M) scoresAll |
// [204M: +0 rcnt, +1K rrows[16384], +256K scoresR[16384*32] (2MB)]
// [208M,224M) partK fp32[64][32][2048] | [224M,240M) partV
// All consumed before k_out runs.
// ---------------------------------------------------------------------------

// fp32 -> fp16, 8 elems/thread, grid-stride
__global__ __launch_bounds__(256) void k_split_h(const float* __restrict__ src,
                                                 short* __restrict__ dst, int n8)
{
    const int stride = gridDim.x * 256;
    for (int i = blockIdx.x * 256 + threadIdx.x; i < n8; i += stride) {
        float4 a = ((const float4*)src)[(size_t)i * 2];
        float4 b = ((const float4*)src)[(size_t)i * 2 + 1];
        float f[8] = {a.x, a.y, a.z, a.w, b.x, b.y, b.z, b.w};
        short h[8];
#pragma unroll
        for (int e = 0; e < 8; ++e) h[e] = f2h(f[e]);
        *(short8*)&dst[(size_t)i * 8] = *(short8*)h;
    }
}

// GEMM1: hidden[16384,1024] = relu(K @ w1^T + b1), single fp16 MFMA.
__global__ __launch_bounds__(256) void k_gemm1(
    const short* __restrict__ kh, const short* __restrict__ w1h,
    const float* __restrict__ cb1, short* __restrict__ hidH)
{
    __shared__ alignas(16) short Ah[128 * 64];
    __shared__ alignas(16) short Bh[128 * 64];

    const int tid = threadIdx.x;
    const int w = tid >> 6, lane = tid & 63;
    const int wr = w & 1, wc = w >> 1;
    const int l31 = lane & 31, lq5 = lane >> 5;

    const int d = blockIdx.x;
    const int xcd = d & 7, t = d >> 3;
    const int jb = t >> 4;
    const int rb = ((t & 15) << 3) | xcd;
    const int row0 = rb * 128, col0 = jb * 128;

    const int s_swz = (lane & 7) ^ (lane >> 3);

    f32x16 acc[2][2] = {};

    for (int kt = 0; kt < 32; ++kt) {
        const int k0 = kt * 64;
        __syncthreads();
#pragma unroll
        for (int q = 0; q < 4; ++q) {
            const int c = w * 4 + q;
            const int r = c * 8 + (lane >> 3);
            const size_t ga = ((size_t)(row0 + r) * HDIM + k0) * 2 + s_swz * 16;
            const size_t gb = ((size_t)(col0 + r) * HDIM + k0) * 2 + s_swz * 16;
            gload16((const char*)kh + ga, &Ah[c * 512]);
            gload16((const char*)w1h + gb, &Bh[c * 512]);
        }
        __syncthreads();
#pragma unroll
        for (int ks = 0; ks < 4; ++ks) {
            const int sw = (((ks * 2 + lq5) ^ (l31 & 7)) << 3);
            short8 aH[2], bH[2];
#pragma unroll
            for (int m = 0; m < 2; ++m)
                aH[m] = *(const short8*)&Ah[(wr * 64 + m * 32 + l31) * 64 + sw];
#pragma unroll
            for (int n = 0; n < 2; ++n)
                bH[n] = *(const short8*)&Bh[(wc * 64 + n * 32 + l31) * 64 + sw];
#pragma unroll
            for (int m = 0; m < 2; ++m)
#pragma unroll
                for (int n = 0; n < 2; ++n)
                    acc[m][n] = __builtin_amdgcn_mfma_f32_32x32x16_f16(aH[m], bH[n], acc[m][n], 0, 0, 0);
        }
    }
#pragma unroll
    for (int n = 0; n < 2; ++n) {
        const int col = col0 + wc * 64 + n * 32 + l31;
        const float bias = cb1[col];
#pragma unroll
        for (int m = 0; m < 2; ++m) {
#pragma unroll
            for (int r = 0; r < 16; ++r) {
                const int row = row0 + wr * 64 + m * 32 + (r & 3) + 8 * (r >> 2) + 4 * lq5;
                float h = acc[m][n][r] + bias;
                hidH[(size_t)row * HHALF + col] = f2h(fmaxf(h, 0.f));
            }
        }
    }
}

// GEMM2: scoresAll[16384,32] = hidden @ w2^T (single fp16 MFMA).
__global__ __launch_bounds__(256) void k_gemm2(
    const short* __restrict__ hidH, const short* __restrict__ w2h,
    float* __restrict__ scoresAll)
{
    __shared__ alignas(16) short Hs[64 * 128];
    __shared__ alignas(16) short W2s[32 * 128];
    __shared__ float ScL[2][64][32];

    const int tid = threadIdx.x;
    const int w = tid >> 6, lane = tid & 63;
    const int l31 = lane & 31, lq5 = lane >> 5;
    const int wr = w & 1;
    const int wk = w >> 1;
    const int row0 = blockIdx.x * 64;

    f32x16 sacc = {};

    for (int jt = 0; jt < 8; ++jt) {
        const int kk0 = jt * 128;
        __syncthreads();
#pragma unroll
        for (int q = 0; q < 4; ++q) {
            const int c = w * 4 + q;
            const int r = c * 4 + (lane >> 4);
            const int s = (lane & 15) ^ (r & 15);
            const size_t g = ((size_t)(row0 + r) * HHALF + kk0) * 2 + s * 16;
            gload16((const char*)hidH + g, &Hs[c * 512]);
        }
#pragma unroll
        for (int q = 0; q < 2; ++q) {
            const int c = w * 2 + q;
            const int r = c * 4 + (lane >> 4);
            const int s = (lane & 15) ^ (r & 15);
            const size_t g = ((size_t)r * HHALF + kk0) * 2 + s * 16;
            gload16((const char*)w2h + g, &W2s[c * 512]);
        }
        __syncthreads();
#pragma unroll
        for (int ks = 0; ks < 4; ++ks) {
            const int slot = wk * 8 + ks * 2 + lq5;
            const int sw = ((slot ^ (l31 & 15)) << 3);
            short8 aH = *(const short8*)&Hs[(wr * 32 + l31) * 128 + sw];
            short8 bH = *(const short8*)&W2s[l31 * 128 + sw];
            sacc = __builtin_amdgcn_mfma_f32_32x32x16_f16(aH, bH, sacc, 0, 0, 0);
        }
    }
#pragma unroll
    for (int r = 0; r < 16; ++r) {
        const int rowL = wr * 32 + (r & 3) + 8 * (r >> 2) + 4 * lq5;
        ScL[wk][rowL][l31] = sacc[r];
    }
    __syncthreads();
    for (int e = tid; e < 64 * NC; e += 256) {
        const int row = e >> 5, c = e & 31;
        scoresAll[(size_t)(row0 + row) * NC + c] = ScL[0][row][c] + ScL[1][row][c];
    }
}

// argmax + low-margin flagging + counts histogram (fused)
__global__ __launch_bounds__(256) void k_argmax(
    const float* __restrict__ scoresAll, const float* __restrict__ cb2,
    int* __restrict__ idx, int* __restrict__ rcnt, int* __restrict__ rrows,
    float* __restrict__ counts)
{
    __shared__ int hist[NC];
    if (threadIdx.x < NC) hist[threadIdx.x] = 0;
    __syncthreads();
    const int row = blockIdx.x * 256 + threadIdx.x;
    const float4* s4 = (const float4*)&scoresAll[(size_t)row * NC];
    float best = -3.4e38f, second = -3.4e38f;
    int bi = 0;
#pragma unroll
    for (int q = 0; q < 8; ++q) {
        float4 v = s4[q];
        float vv[4] = {v.x, v.y, v.z, v.w};
#pragma unroll
        for (int e = 0; e < 4; ++e) {
            const int c = q * 4 + e;
            const float s = vv[e] + cb2[c];
            if (s > best) { second = best; best = s; bi = c; }
            else if (s > second) second = s;
        }
    }
    idx[row] = bi;
    atomicAdd(&hist[bi], 1);
    if (best - second < REFINE_TH) {
        int slot = atomicAdd(rcnt, 1);
        if (slot < REFINE_CAP) rrows[slot] = row;
    }
    __syncthreads();
    if (threadIdx.x < NC)
        atomicAdd(&counts[threadIdx.x], (float)hist[threadIdx.x]);
}

// exact fp32 recompute of scores for flagged rows
__global__ __launch_bounds__(256) void k_refine_gemm(
    const float* __restrict__ K, const float* __restrict__ cw1,
    const float* __restrict__ cb1, const float* __restrict__ cw2,
    const int* __restrict__ rcnt, const int* __restrict__ rrows,
    float* __restrict__ scoresR)
{
    const int cnt = min(*rcnt, REFINE_CAP);
    if (cnt == 0) return;
    const int units = ((cnt + 63) >> 6) * 16;
    __shared__ float KsT[64][68];
    __shared__ float WsT[64][68];
    __shared__ float Hs2[64][68];
    __shared__ float W2f[NC][68];

    const int tid = threadIdx.x;
    const int ti = tid & 15, tj = tid >> 4;
    const int si = tid & 63, sc0 = (tid >> 6) * 8;

    for (int u = blockIdx.x; u < units; u += gridDim.x) {
        const int rc = u >> 4, jt = u & 15, j0 = jt * 64;
        const int M = min(cnt - rc * 64, 64);

        float hacc[4][4];
#pragma unroll
        for (int a = 0; a < 4; ++a)
#pragma unroll
            for (int b = 0; b < 4; ++b) hacc[a][b] = 0.f;

        for (int kt = 0; kt < 32; ++kt) {
            const int k0 = kt * 64;
            __syncthreads();
            {
                const int r  = tid >> 2;
                const int kb = (tid & 3) * 16;
                const int grow = rrows[rc * 64 + min(r, M - 1)];
#pragma unroll
                for (int q = 0; q < 4; ++q) {
                    float4 v = *(const float4*)&K[(size_t)grow * HDIM + k0 + kb + q * 4];
                    KsT[kb + q * 4 + 0][r] = v.x; KsT[kb + q * 4 + 1][r] = v.y;
                    KsT[kb + q * 4 + 2][r] = v.z; KsT[kb + q * 4 + 3][r] = v.w;
                }
                const int j = tid >> 2;
#pragma unroll
                for (int q = 0; q < 4; ++q) {
                    float4 v = *(const float4*)&cw1[(size_t)(j0 + j) * HDIM + k0 + kb + q * 4];
                    WsT[kb + q * 4 + 0][j] = v.x; WsT[kb + q * 4 + 1][j] = v.y;
                    WsT[kb + q * 4 + 2][j] = v.z; WsT[kb + q * 4 + 3][j] = v.w;
                }
            }
            __syncthreads();
#pragma unroll 4
            for (int k = 0; k < 64; ++k) {
                float4 a = *(float4*)&KsT[k][ti * 4];
                float4 b = *(float4*)&WsT[k][tj * 4];
                float av[4] = {a.x, a.y, a.z, a.w};
                float bv[4] = {b.x, b.y, b.z, b.w};
#pragma unroll
                for (int di = 0; di < 4; ++di)
#pragma unroll
                    for (int dj = 0; dj < 4; ++dj)
                        hacc[di][dj] += av[di] * bv[dj];
            }
        }
        __syncthreads();
#pragma unroll
        for (int di = 0; di < 4; ++di)
#pragma unroll
            for (int dj = 0; dj < 4; ++dj) {
                float h = hacc[di][dj] + cb1[j0 + tj * 4 + dj];
                Hs2[ti * 4 + di][tj * 4 + dj] = fmaxf(h, 0.f);
            }
        {
            const int c  = tid >> 3;
            const int jq = (tid & 7) * 8;
            *(float4*)&W2f[c][jq]     = *(const float4*)&cw2[(size_t)c * HHALF + j0 + jq];
            *(float4*)&W2f[c][jq + 4] = *(const float4*)&cw2[(size_t)c * HHALF + j0 + jq + 4];
        }
        __syncthreads();
        float sacc[8];
#pragma unroll
        for (int q = 0; q < 8; ++q) sacc[q] = 0.f;
        for (int j = 0; j < 64; ++j) {
            float h = Hs2[si][j];
#pragma unroll
            for (int q = 0; q < 8; ++q) sacc[q] += h * W2f[sc0 + q][j];
        }
        if (si < M) {
#pragma unroll
            for (int q = 0; q < 8; ++q)
                atomicAdd(&scoresR[(size_t)(rc * 64 + si) * NC + sc0 + q], sacc[q]);
        }
        __syncthreads();
    }
}

__global__ __launch_bounds__(256) void k_refine_fix(
    const int* __restrict__ rcnt, const int* __restrict__ rrows,
    const float* __restrict__ scoresR, const float* __restrict__ cb2,
    int* __restrict__ idx, float* __restrict__ counts)
{
    const int cnt = min(*rcnt, REFINE_CAP);
    const int t = blockIdx.x * 256 + threadIdx.x;
    if (t >= cnt) return;
    float best = -3.4e38f;
    int bi = 0;
    for (int c = 0; c < NC; ++c) {
        float v = scoresR[(size_t)t * NC + c] + cb2[c];
        if (v > best) { best = v; bi = c; }
    }
    const int row = rrows[t];
    const int old = idx[row];
    if (old != bi) {
        idx[row] = bi;
        atomicAdd(&counts[old], -1.f);
        atomicAdd(&counts[bi], 1.f);
    }
}

// Phase A of segment-sum: dense partial sums, no global atomics, no skew.
// grid (rb=64, cb=8, kv=2). Block: 256 consecutive rows x 256-col slice.
// Wave w handles rows it*4+w; lane covers 4 cols (float4). K/V loads are
// idx-independent -> deep pipelining. LDS atomics accumulate per-centroid.
__global__ __launch_bounds__(256) void k_psum(
    const float* __restrict__ K, const float* __restrict__ V,
    const int* __restrict__ idx, float* __restrict__ partK,
    float* __restrict__ partV)
{
    __shared__ float ps[NC][256];
    const int rb = blockIdx.x;
    const int cb = blockIdx.y;
    const float* X = blockIdx.z ? V : K;
    float* P       = blockIdx.z ? partV : partK;
    const int tid = threadIdx.x;
    const int w = tid >> 6, lane = tid & 63;
    const int col0 = cb * 256;

    for (int e = tid; e < NC * 256; e += 256) ((float*)ps)[e] = 0.f;
    __syncthreads();

    const int row0 = rb * 256;
#pragma unroll 4
    for (int it = 0; it < 64; ++it) {
        const int row = row0 + it * 4 + w;
        const int c = idx[row];
        const float4 v = *(const float4*)&X[(size_t)row * HDIM + col0 + lane * 4];
        atomicAdd(&ps[c][lane * 4 + 0], v.x);
        atomicAdd(&ps[c][lane * 4 + 1], v.y);
        atomicAdd(&ps[c][lane * 4 + 2], v.z);
        atomicAdd(&ps[c][lane * 4 + 3], v.w);
    }
    __syncthreads();
    for (int e = tid; e < NC * 256; e += 256) {
        const int c = e >> 8, t = e & 255;
        P[((size_t)rb * NC + c) * HDIM + col0 + t] = ps[c][t];
    }
}

// Phase B: reduce 64 rb-partials -> kcent/vcent (plain writes).
__global__ __launch_bounds__(256) void k_reduce(
    const float* __restrict__ partK, const float* __restrict__ partV,
    float* __restrict__ kcent, float* __restrict__ vcent)
{
    const int e = blockIdx.x * 256 + threadIdx.x;  // 65536 = 32*2048
    float sk = 0.f, sv = 0.f;
#pragma unroll 8
    for (int rb = 0; rb < 64; ++rb) {
        sk += partK[(size_t)rb * (NC * HDIM) + e];
        sv += partV[(size_t)rb * (NC * HDIM) + e];
    }
    kcent[e] = sk;
    vcent[e] = sv;
}

__global__ __launch_bounds__(256) void k_final1(float* __restrict__ kc,
                                                float* __restrict__ vc,
                                                const float* __restrict__ counts)
{
    const int e = blockIdx.x * 256 + threadIdx.x;
    const int c = e >> 11;
    const float denom = fmaxf(counts[c], 1.f);
    kc[e] /= denom;
    vc[e] /= denom;
}

__global__ __launch_bounds__(256) void k_final2(
    float* __restrict__ kc, float* __restrict__ vc,
    const float* __restrict__ counts, const float* __restrict__ nk,
    const float* __restrict__ nv)
{
    const int e = blockIdx.x * 256 + threadIdx.x;
    const int c = e >> 11;
    const int h = e & 2047;
    if (counts[c] == 0.f) {
        int src = 0;
        float best = counts[0];
        for (int j = 1; j < NC; ++j) {
            float v = counts[j];
            if (v > best) { best = v; src = j; }
        }
        kc[e] = kc[src * HDIM + h] + 0.1f * nk[e];
        vc[e] = vc[src * HDIM + h] + 0.1f * nv[e];
    }
}

// split-K MLP layer over the 32 centroids: grid (jt=32, kv=2, ks=4).
__global__ __launch_bounds__(256) void k_mlp_sk(
    const float* __restrict__ Xk, const float* __restrict__ Xv,
    const float* __restrict__ W, float* __restrict__ Ok,
    float* __restrict__ Ov)
{
    __shared__ float Xs[32][65];
    __shared__ float Wt[64][65];
    const float* X = blockIdx.y ? Xv : Xk;
    float* O       = blockIdx.y ? Ov : Ok;
    const int tid   = threadIdx.x;
    const int jbase = blockIdx.x * 64;
    const int kbase = blockIdx.z * 512;
    const int ti = tid & 7;
    const int tj = tid >> 3;
    float acc[4][2];
#pragma unroll
    for (int a = 0; a < 4; ++a) { acc[a][0] = 0.f; acc[a][1] = 0.f; }

    for (int kt = 0; kt < 8; ++kt) {
        const int k0 = kbase + kt * 64;
        __syncthreads();
        {
            const int f4 = tid & 15;
            const int r  = tid >> 4;
#pragma unroll
            for (int rr = 0; rr < 2; ++rr) {
                const int row = r + rr * 16;
                float4 xv = *(const float4*)&X[(size_t)row * HDIM + k0 + f4 * 4];
                Xs[row][f4 * 4 + 0] = xv.x; Xs[row][f4 * 4 + 1] = xv.y;
                Xs[row][f4 * 4 + 2] = xv.z; Xs[row][f4 * 4 + 3] = xv.w;
            }
#pragma unroll
            for (int rr = 0; rr < 4; ++rr) {
                const int row = r + rr * 16;
                float4 wv = *(const float4*)&W[(size_t)(jbase + row) * HDIM + k0 + f4 * 4];
                Wt[row][f4 * 4 + 0] = wv.x; Wt[row][f4 * 4 + 1] = wv.y;
                Wt[row][f4 * 4 + 2] = wv.z; Wt[row][f4 * 4 + 3] = wv.w;
            }
        }
        __syncthreads();
#pragma unroll 8
        for (int k = 0; k < 64; ++k) {
            float a[4], b[2];
#pragma unroll
            for (int d = 0; d < 4; ++d) a[d] = Xs[ti * 4 + d][k];
#pragma unroll
            for (int d = 0; d < 2; ++d) b[d] = Wt[tj * 2 + d][k];
#pragma unroll
            for (int d = 0; d < 4; ++d)
#pragma unroll
                for (int e2 = 0; e2 < 2; ++e2)
                    acc[d][e2] += a[d] * b[e2];
        }
    }
#pragma unroll
    for (int d = 0; d < 4; ++d)
#pragma unroll
        for (int e2 = 0; e2 < 2; ++e2) {
            const int i = ti * 4 + d;
            const int j = jbase + tj * 2 + e2;
            atomicAdd(&O[(size_t)i * HDIM + j], acc[d][e2]);
        }
}

__global__ __launch_bounds__(256) void k_bias_act(
    float* __restrict__ Ak, float* __restrict__ Av,
    const float* __restrict__ bias, int relu)
{
    const int e = blockIdx.x * 256 + threadIdx.x;
    const int j = e & 2047;
    const float b = bias[j];
    float vk = Ak[e] + b;
    float vv = Av[e] + b;
    if (relu) { vk = fmaxf(vk, 0.f); vv = fmaxf(vv, 0.f); }
    Ak[e] = vk;
    Av[e] = vv;
}

__global__ __launch_bounds__(256) void k_out(
    const float* __restrict__ K, const float* __restrict__ V,
    const float* __restrict__ imp, const int* __restrict__ idx,
    const float* __restrict__ tck, const float* __restrict__ tcv,
    float* __restrict__ ok, float* __restrict__ ov)
{
    const size_t total = (size_t)NROWS * (HDIM / 4);
    for (size_t e = (size_t)blockIdx.x * 256 + threadIdx.x; e < total;
         e += (size_t)gridDim.x * 256) {
        const int r = (int)(e >> 9);
        const int q = (int)(e & 511);
        const bool pass = imp[r] > 0.1f;
        const int c = idx[r];
        const float4* sk = pass ? (const float4*)&K[(size_t)r * HDIM]
                                : (const float4*)&tck[(size_t)c * HDIM];
        const float4* sv = pass ? (const float4*)&V[(size_t)r * HDIM]
                                : (const float4*)&tcv[(size_t)c * HDIM];
        ((float4*)ok)[e] = sk[q];
        ((float4*)ov)[e] = sv[q];
    }
}

extern "C" void kernel_launch(void* const* d_in, const int* in_sizes, int n_in,
                              void* d_out, int out_size, void* d_ws,
                              size_t ws_size, hipStream_t stream)
{
    (void)in_sizes; (void)n_in; (void)out_size; (void)ws_size;
    const float* keys   = (const float*)d_in[0];
    const float* values = (const float*)d_in[1];
    const float* imp    = (const float*)d_in[2];
    const float* cw1    = (const float*)d_in[3];
    const float* cb1    = (const float*)d_in[4];
    const float* cw2    = (const float*)d_in[5];
    const float* cb2    = (const float*)d_in[6];
    const float* tw1    = (const float*)d_in[7];
    const float* tb1    = (const float*)d_in[8];
    const float* tw2    = (const float*)d_in[9];
    const float* tb2    = (const float*)d_in[10];
    const float* nk     = (const float*)d_in[11];
    const float* nv     = (const float*)d_in[12];

    char* ws = (char*)d_ws;
    int*   idx    = (int*)ws;
    float* counts = (float*)(ws + (64 << 10));
    float* kcent  = (float*)(ws + (128 << 10));
    float* vcent  = (float*)(ws + (384 << 10));
    float* hk     = (float*)(ws + (640 << 10));
    float* hv     = (float*)(ws + (896 << 10));
    float* tck    = (float*)(ws + (1152 << 10));
    float* tcv    = (float*)(ws + (1408 << 10));

    const size_t MB = (size_t)1 << 20;
    char* ob = (char*)d_out;
    short* kh   = (short*)(ob);
    short* hidH = (short*)(ob + 128 * MB);
    short* w1h  = (short*)(ob + 192 * MB);
    short* w2h  = (short*)(ob + 200 * MB);
    float* scoresAll = (float*)(ob + 201 * MB);
    char*  sb = ob + 204 * MB;
    int*   rcnt    = (int*)(sb);
    int*   rrows   = (int*)(sb + 1024);
    float* scoresR = (float*)(sb + (256 << 10));
    float* partK   = (float*)(ob + 208 * MB);
    float* partV   = (float*)(ob + 224 * MB);
    float* ok = (float*)d_out;
    float* ov = ok + (size_t)NROWS * HDIM;

    // zero atomic targets: counts + hk/hv/tck/tcv (+ kcent/vcent harmless)
    hipMemsetAsync(ws + (64 << 10), 0, (1664 - 64) << 10, stream);
    hipMemsetAsync(sb, 0, (256 << 10) + 2 * MB, stream);

    k_split_h<<<2048, 256, 0, stream>>>(keys, kh, NROWS * HDIM / 8);
    k_split_h<<<256, 256, 0, stream>>>(cw1, w1h, HHALF * HDIM / 8);
    k_split_h<<<16, 256, 0, stream>>>(cw2, w2h, NC * HHALF / 8);
    k_gemm1<<<1024, 256, 0, stream>>>(kh, w1h, cb1, hidH);
    k_gemm2<<<NROWS / 64, 256, 0, stream>>>(hidH, w2h, scoresAll);
    k_argmax<<<NROWS / 256, 256, 0, stream>>>(scoresAll, cb2, idx, rcnt, rrows, counts);
    k_refine_gemm<<<256, 256, 0, stream>>>(keys, cw1, cb1, cw2, rcnt, rrows, scoresR);
    k_refine_fix<<<NROWS / 256, 256, 0, stream>>>(rcnt, rrows, scoresR, cb2, idx, counts);
    k_psum<<<dim3(64, 8, 2), 256, 0, stream>>>(keys, values, idx, partK, partV);
    k_reduce<<<NC * HDIM / 256, 256, 0, stream>>>(partK, partV, kcent, vcent);
    k_final1<<<(NC * HDIM) / 256, 256, 0, stream>>>(kcent, vcent, counts);
    k_final2<<<(NC * HDIM) / 256, 256, 0, stream>>>(kcent, vcent, counts, nk, nv);
    k_mlp_sk<<<dim3(32, 2, 4), 256, 0, stream>>>(kcent, vcent, tw1, hk, hv);
    k_bias_act<<<256, 256, 0, stream>>>(hk, hv, tb1, 1);
    k_mlp_sk<<<dim3(32, 2, 4), 256, 0, stream>>>(hk, hv, tw2, tck, tcv);
    k_bias_act<<<256, 256, 0, stream>>>(tck, tcv, tb2, 0);
    k_out<<<2048, 256, 0, stream>>>(keys, values, imp, idx, tck, tcv, ok, ov);
}

// Round 9
// 488.173 us; speedup vs baseline: 1.5578x; 1.5578x over previous
//
#include <hip/hip_runtime.h>
#include <hip/hip_bf16.h>

#define NROWS 16384
#define HDIM  2048
#define HHALF 1024
#define NC    32
#define REFINE_TH 0.012f
#define REFINE_CAP 16384

typedef __attribute__((ext_vector_type(8)))  short  short8;
typedef __attribute__((ext_vector_type(16))) float  f32x16;

typedef __attribute__((address_space(3))) void lds_void;
typedef const __attribute__((address_space(1))) void gbl_void;

static __device__ __forceinline__ short f2h(float f) {
    _Float16 h = (_Float16)f;
    return *(short*)&h;
}
static __device__ __forceinline__ void gload16(const void* g, void* l) {
    __builtin_amdgcn_global_load_lds((gbl_void*)g, (lds_void*)l, 16, 0, 0);
}

// ---------------------------------------------------------------------------
// ws: [0,64K) idx | [64K,+128) counts | [128K,384K) kcent | [384K,640K) vcent
// [640K,896K) hk | [896K,1152K) hv | [1152K,1408K) tck | [1408K,1664K) tcv
//
// d_out (256MiB) = scratch until k_out overwrites it:
// [0,64M) kh (fp16 keys) | [128M,160M) hidH (fp16) | [192M,196M) w1h |
// [200M,+64K) w2h | [201M,+2M) scoresAll |
// [204M: +0 rcnt, +1K rrows[16384], +256K scoresR[16384*32] (2MB)]
// [208M,224M) partK fp32[64][32][2048] | [224M,240M) partV
// All consumed before k_out runs.
// ---------------------------------------------------------------------------

// fp32 -> fp16, 8 elems/thread, grid-stride
__global__ __launch_bounds__(256) void k_split_h(const float* __restrict__ src,
                                                 short* __restrict__ dst, int n8)
{
    const int stride = gridDim.x * 256;
    for (int i = blockIdx.x * 256 + threadIdx.x; i < n8; i += stride) {
        float4 a = ((const float4*)src)[(size_t)i * 2];
        float4 b = ((const float4*)src)[(size_t)i * 2 + 1];
        float f[8] = {a.x, a.y, a.z, a.w, b.x, b.y, b.z, b.w};
        short h[8];
#pragma unroll
        for (int e = 0; e < 8; ++e) h[e] = f2h(f[e]);
        *(short8*)&dst[(size_t)i * 8] = *(short8*)h;
    }
}

// GEMM1: hidden[16384,1024] = relu(K @ w1^T + b1), single fp16 MFMA.
__global__ __launch_bounds__(256) void k_gemm1(
    const short* __restrict__ kh, const short* __restrict__ w1h,
    const float* __restrict__ cb1, short* __restrict__ hidH)
{
    __shared__ alignas(16) short Ah[128 * 64];
    __shared__ alignas(16) short Bh[128 * 64];

    const int tid = threadIdx.x;
    const int w = tid >> 6, lane = tid & 63;
    const int wr = w & 1, wc = w >> 1;
    const int l31 = lane & 31, lq5 = lane >> 5;

    const int d = blockIdx.x;
    const int xcd = d & 7, t = d >> 3;
    const int jb = t >> 4;
    const int rb = ((t & 15) << 3) | xcd;
    const int row0 = rb * 128, col0 = jb * 128;

    const int s_swz = (lane & 7) ^ (lane >> 3);

    f32x16 acc[2][2] = {};

    for (int kt = 0; kt < 32; ++kt) {
        const int k0 = kt * 64;
        __syncthreads();
#pragma unroll
        for (int q = 0; q < 4; ++q) {
            const int c = w * 4 + q;
            const int r = c * 8 + (lane >> 3);
            const size_t ga = ((size_t)(row0 + r) * HDIM + k0) * 2 + s_swz * 16;
            const size_t gb = ((size_t)(col0 + r) * HDIM + k0) * 2 + s_swz * 16;
            gload16((const char*)kh + ga, &Ah[c * 512]);
            gload16((const char*)w1h + gb, &Bh[c * 512]);
        }
        __syncthreads();
#pragma unroll
        for (int ks = 0; ks < 4; ++ks) {
            const int sw = (((ks * 2 + lq5) ^ (l31 & 7)) << 3);
            short8 aH[2], bH[2];
#pragma unroll
            for (int m = 0; m < 2; ++m)
                aH[m] = *(const short8*)&Ah[(wr * 64 + m * 32 + l31) * 64 + sw];
#pragma unroll
            for (int n = 0; n < 2; ++n)
                bH[n] = *(const short8*)&Bh[(wc * 64 + n * 32 + l31) * 64 + sw];
#pragma unroll
            for (int m = 0; m < 2; ++m)
#pragma unroll
                for (int n = 0; n < 2; ++n)
                    acc[m][n] = __builtin_amdgcn_mfma_f32_32x32x16_f16(aH[m], bH[n], acc[m][n], 0, 0, 0);
        }
    }
#pragma unroll
    for (int n = 0; n < 2; ++n) {
        const int col = col0 + wc * 64 + n * 32 + l31;
        const float bias = cb1[col];
#pragma unroll
        for (int m = 0; m < 2; ++m) {
#pragma unroll
            for (int r = 0; r < 16; ++r) {
                const int row = row0 + wr * 64 + m * 32 + (r & 3) + 8 * (r >> 2) + 4 * lq5;
                float h = acc[m][n][r] + bias;
                hidH[(size_t)row * HHALF + col] = f2h(fmaxf(h, 0.f));
            }
        }
    }
}

// GEMM2: scoresAll[16384,32] = hidden @ w2^T (single fp16 MFMA).
__global__ __launch_bounds__(256) void k_gemm2(
    const short* __restrict__ hidH, const short* __restrict__ w2h,
    float* __restrict__ scoresAll)
{
    __shared__ alignas(16) short Hs[64 * 128];
    __shared__ alignas(16) short W2s[32 * 128];
    __shared__ float ScL[2][64][32];

    const int tid = threadIdx.x;
    const int w = tid >> 6, lane = tid & 63;
    const int l31 = lane & 31, lq5 = lane >> 5;
    const int wr = w & 1;
    const int wk = w >> 1;
    const int row0 = blockIdx.x * 64;

    f32x16 sacc = {};

    for (int jt = 0; jt < 8; ++jt) {
        const int kk0 = jt * 128;
        __syncthreads();
#pragma unroll
        for (int q = 0; q < 4; ++q) {
            const int c = w * 4 + q;
            const int r = c * 4 + (lane >> 4);
            const int s = (lane & 15) ^ (r & 15);
            const size_t g = ((size_t)(row0 + r) * HHALF + kk0) * 2 + s * 16;
            gload16((const char*)hidH + g, &Hs[c * 512]);
        }
#pragma unroll
        for (int q = 0; q < 2; ++q) {
            const int c = w * 2 + q;
            const int r = c * 4 + (lane >> 4);
            const int s = (lane & 15) ^ (r & 15);
            const size_t g = ((size_t)r * HHALF + kk0) * 2 + s * 16;
            gload16((const char*)w2h + g, &W2s[c * 512]);
        }
        __syncthreads();
#pragma unroll
        for (int ks = 0; ks < 4; ++ks) {
            const int slot = wk * 8 + ks * 2 + lq5;
            const int sw = ((slot ^ (l31 & 15)) << 3);
            short8 aH = *(const short8*)&Hs[(wr * 32 + l31) * 128 + sw];
            short8 bH = *(const short8*)&W2s[l31 * 128 + sw];
            sacc = __builtin_amdgcn_mfma_f32_32x32x16_f16(aH, bH, sacc, 0, 0, 0);
        }
    }
#pragma unroll
    for (int r = 0; r < 16; ++r) {
        const int rowL = wr * 32 + (r & 3) + 8 * (r >> 2) + 4 * lq5;
        ScL[wk][rowL][l31] = sacc[r];
    }
    __syncthreads();
    for (int e = tid; e < 64 * NC; e += 256) {
        const int row = e >> 5, c = e & 31;
        scoresAll[(size_t)(row0 + row) * NC + c] = ScL[0][row][c] + ScL[1][row][c];
    }
}

// argmax + low-margin flagging + counts histogram (fused)
__global__ __launch_bounds__(256) void k_argmax(
    const float* __restrict__ scoresAll, const float* __restrict__ cb2,
    int* __restrict__ idx, int* __restrict__ rcnt, int* __restrict__ rrows,
    float* __restrict__ counts)
{
    __shared__ int hist[NC];
    if (threadIdx.x < NC) hist[threadIdx.x] = 0;
    __syncthreads();
    const int row = blockIdx.x * 256 + threadIdx.x;
    const float4* s4 = (const float4*)&scoresAll[(size_t)row * NC];
    float best = -3.4e38f, second = -3.4e38f;
    int bi = 0;
#pragma unroll
    for (int q = 0; q < 8; ++q) {
        float4 v = s4[q];
        float vv[4] = {v.x, v.y, v.z, v.w};
#pragma unroll
        for (int e = 0; e < 4; ++e) {
            const int c = q * 4 + e;
            const float s = vv[e] + cb2[c];
            if (s > best) { second = best; best = s; bi = c; }
            else if (s > second) second = s;
        }
    }
    idx[row] = bi;
    atomicAdd(&hist[bi], 1);
    if (best - second < REFINE_TH) {
        int slot = atomicAdd(rcnt, 1);
        if (slot < REFINE_CAP) rrows[slot] = row;
    }
    __syncthreads();
    if (threadIdx.x < NC)
        atomicAdd(&counts[threadIdx.x], (float)hist[threadIdx.x]);
}

// exact fp32 recompute of scores for flagged rows
__global__ __launch_bounds__(256) void k_refine_gemm(
    const float* __restrict__ K, const float* __restrict__ cw1,
    const float* __restrict__ cb1, const float* __restrict__ cw2,
    const int* __restrict__ rcnt, const int* __restrict__ rrows,
    float* __restrict__ scoresR)
{
    const int cnt = min(*rcnt, REFINE_CAP);
    if (cnt == 0) return;
    const int units = ((cnt + 63) >> 6) * 16;
    __shared__ float KsT[64][68];
    __shared__ float WsT[64][68];
    __shared__ float Hs2[64][68];
    __shared__ float W2f[NC][68];

    const int tid = threadIdx.x;
    const int ti = tid & 15, tj = tid >> 4;
    const int si = tid & 63, sc0 = (tid >> 6) * 8;

    for (int u = blockIdx.x; u < units; u += gridDim.x) {
        const int rc = u >> 4, jt = u & 15, j0 = jt * 64;
        const int M = min(cnt - rc * 64, 64);

        float hacc[4][4];
#pragma unroll
        for (int a = 0; a < 4; ++a)
#pragma unroll
            for (int b = 0; b < 4; ++b) hacc[a][b] = 0.f;

        for (int kt = 0; kt < 32; ++kt) {
            const int k0 = kt * 64;
            __syncthreads();
            {
                const int r  = tid >> 2;
                const int kb = (tid & 3) * 16;
                const int grow = rrows[rc * 64 + min(r, M - 1)];
#pragma unroll
                for (int q = 0; q < 4; ++q) {
                    float4 v = *(const float4*)&K[(size_t)grow * HDIM + k0 + kb + q * 4];
                    KsT[kb + q * 4 + 0][r] = v.x; KsT[kb + q * 4 + 1][r] = v.y;
                    KsT[kb + q * 4 + 2][r] = v.z; KsT[kb + q * 4 + 3][r] = v.w;
                }
                const int j = tid >> 2;
#pragma unroll
                for (int q = 0; q < 4; ++q) {
                    float4 v = *(const float4*)&cw1[(size_t)(j0 + j) * HDIM + k0 + kb + q * 4];
                    WsT[kb + q * 4 + 0][j] = v.x; WsT[kb + q * 4 + 1][j] = v.y;
                    WsT[kb + q * 4 + 2][j] = v.z; WsT[kb + q * 4 + 3][j] = v.w;
                }
            }
            __syncthreads();
#pragma unroll 4
            for (int k = 0; k < 64; ++k) {
                float4 a = *(float4*)&KsT[k][ti * 4];
                float4 b = *(float4*)&WsT[k][tj * 4];
                float av[4] = {a.x, a.y, a.z, a.w};
                float bv[4] = {b.x, b.y, b.z, b.w};
#pragma unroll
                for (int di = 0; di < 4; ++di)
#pragma unroll
                    for (int dj = 0; dj < 4; ++dj)
                        hacc[di][dj] += av[di] * bv[dj];
            }
        }
        __syncthreads();
#pragma unroll
        for (int di = 0; di < 4; ++di)
#pragma unroll
            for (int dj = 0; dj < 4; ++dj) {
                float h = hacc[di][dj] + cb1[j0 + tj * 4 + dj];
                Hs2[ti * 4 + di][tj * 4 + dj] = fmaxf(h, 0.f);
            }
        {
            const int c  = tid >> 3;
            const int jq = (tid & 7) * 8;
            *(float4*)&W2f[c][jq]     = *(const float4*)&cw2[(size_t)c * HHALF + j0 + jq];
            *(float4*)&W2f[c][jq + 4] = *(const float4*)&cw2[(size_t)c * HHALF + j0 + jq + 4];
        }
        __syncthreads();
        float sacc[8];
#pragma unroll
        for (int q = 0; q < 8; ++q) sacc[q] = 0.f;
        for (int j = 0; j < 64; ++j) {
            float h = Hs2[si][j];
#pragma unroll
            for (int q = 0; q < 8; ++q) sacc[q] += h * W2f[sc0 + q][j];
        }
        if (si < M) {
#pragma unroll
            for (int q = 0; q < 8; ++q)
                atomicAdd(&scoresR[(size_t)(rc * 64 + si) * NC + sc0 + q], sacc[q]);
        }
        __syncthreads();
    }
}

__global__ __launch_bounds__(256) void k_refine_fix(
    const int* __restrict__ rcnt, const int* __restrict__ rrows,
    const float* __restrict__ scoresR, const float* __restrict__ cb2,
    int* __restrict__ idx, float* __restrict__ counts)
{
    const int cnt = min(*rcnt, REFINE_CAP);
    const int t = blockIdx.x * 256 + threadIdx.x;
    if (t >= cnt) return;
    float best = -3.4e38f;
    int bi = 0;
    for (int c = 0; c < NC; ++c) {
        float v = scoresR[(size_t)t * NC + c] + cb2[c];
        if (v > best) { best = v; bi = c; }
    }
    const int row = rrows[t];
    const int old = idx[row];
    if (old != bi) {
        idx[row] = bi;
        atomicAdd(&counts[old], -1.f);
        atomicAdd(&counts[bi], 1.f);
    }
}

// Phase A of segment-sum: exclusive column ownership -> NO atomics, NO
// barriers. grid (rb=64, cb=8, kv=2). Thread tid owns column cb*256+tid;
// all threads sweep the block's 256 rows. LDS RMW ps[c][tid]: addresses
// c*256+tid -> 2-way bank alias (free). Global: 4B/lane coalesced stream.
__global__ __launch_bounds__(256) void k_psum(
    const float* __restrict__ K, const float* __restrict__ V,
    const int* __restrict__ idx, float* __restrict__ partK,
    float* __restrict__ partV)
{
    __shared__ float ps[NC][256];
    const int rb = blockIdx.x;
    const int cb = blockIdx.y;
    const float* X = blockIdx.z ? V : K;
    float* P       = blockIdx.z ? partV : partK;
    const int tid = threadIdx.x;
    const int col = cb * 256 + tid;

#pragma unroll
    for (int c = 0; c < NC; ++c) ps[c][tid] = 0.f;
    // no barrier: ps[*][tid] is touched only by this thread

    const int row0 = rb * 256;
#pragma unroll 4
    for (int r = 0; r < 256; ++r) {
        const int row = row0 + r;
        const int c = idx[row];                        // wave-uniform scalar
        const float v = X[(size_t)row * HDIM + col];   // coalesced
        ps[c][tid] += v;                               // exclusive owner
    }

#pragma unroll
    for (int c = 0; c < NC; ++c)
        P[((size_t)rb * NC + c) * HDIM + col] = ps[c][tid];
}

// Phase B: reduce 64 rb-partials -> kcent/vcent (plain writes).
__global__ __launch_bounds__(256) void k_reduce(
    const float* __restrict__ partK, const float* __restrict__ partV,
    float* __restrict__ kcent, float* __restrict__ vcent)
{
    const int e = blockIdx.x * 256 + threadIdx.x;  // 65536 = 32*2048
    float sk = 0.f, sv = 0.f;
#pragma unroll 8
    for (int rb = 0; rb < 64; ++rb) {
        sk += partK[(size_t)rb * (NC * HDIM) + e];
        sv += partV[(size_t)rb * (NC * HDIM) + e];
    }
    kcent[e] = sk;
    vcent[e] = sv;
}

__global__ __launch_bounds__(256) void k_final1(float* __restrict__ kc,
                                                float* __restrict__ vc,
                                                const float* __restrict__ counts)
{
    const int e = blockIdx.x * 256 + threadIdx.x;
    const int c = e >> 11;
    const float denom = fmaxf(counts[c], 1.f);
    kc[e] /= denom;
    vc[e] /= denom;
}

__global__ __launch_bounds__(256) void k_final2(
    float* __restrict__ kc, float* __restrict__ vc,
    const float* __restrict__ counts, const float* __restrict__ nk,
    const float* __restrict__ nv)
{
    const int e = blockIdx.x * 256 + threadIdx.x;
    const int c = e >> 11;
    const int h = e & 2047;
    if (counts[c] == 0.f) {
        int src = 0;
        float best = counts[0];
        for (int j = 1; j < NC; ++j) {
            float v = counts[j];
            if (v > best) { best = v; src = j; }
        }
        kc[e] = kc[src * HDIM + h] + 0.1f * nk[e];
        vc[e] = vc[src * HDIM + h] + 0.1f * nv[e];
    }
}

// split-K MLP layer over the 32 centroids: grid (jt=32, kv=2, ks=4).
__global__ __launch_bounds__(256) void k_mlp_sk(
    const float* __restrict__ Xk, const float* __restrict__ Xv,
    const float* __restrict__ W, float* __restrict__ Ok,
    float* __restrict__ Ov)
{
    __shared__ float Xs[32][65];
    __shared__ float Wt[64][65];
    const float* X = blockIdx.y ? Xv : Xk;
    float* O       = blockIdx.y ? Ov : Ok;
    const int tid   = threadIdx.x;
    const int jbase = blockIdx.x * 64;
    const int kbase = blockIdx.z * 512;
    const int ti = tid & 7;
    const int tj = tid >> 3;
    float acc[4][2];
#pragma unroll
    for (int a = 0; a < 4; ++a) { acc[a][0] = 0.f; acc[a][1] = 0.f; }

    for (int kt = 0; kt < 8; ++kt) {
        const int k0 = kbase + kt * 64;
        __syncthreads();
        {
            const int f4 = tid & 15;
            const int r  = tid >> 4;
#pragma unroll
            for (int rr = 0; rr < 2; ++rr) {
                const int row = r + rr * 16;
                float4 xv = *(const float4*)&X[(size_t)row * HDIM + k0 + f4 * 4];
                Xs[row][f4 * 4 + 0] = xv.x; Xs[row][f4 * 4 + 1] = xv.y;
                Xs[row][f4 * 4 + 2] = xv.z; Xs[row][f4 * 4 + 3] = xv.w;
            }
#pragma unroll
            for (int rr = 0; rr < 4; ++rr) {
                const int row = r + rr * 16;
                float4 wv = *(const float4*)&W[(size_t)(jbase + row) * HDIM + k0 + f4 * 4];
                Wt[row][f4 * 4 + 0] = wv.x; Wt[row][f4 * 4 + 1] = wv.y;
                Wt[row][f4 * 4 + 2] = wv.z; Wt[row][f4 * 4 + 3] = wv.w;
            }
        }
        __syncthreads();
#pragma unroll 8
        for (int k = 0; k < 64; ++k) {
            float a[4], b[2];
#pragma unroll
            for (int d = 0; d < 4; ++d) a[d] = Xs[ti * 4 + d][k];
#pragma unroll
            for (int d = 0; d < 2; ++d) b[d] = Wt[tj * 2 + d][k];
#pragma unroll
            for (int d = 0; d < 4; ++d)
#pragma unroll
                for (int e2 = 0; e2 < 2; ++e2)
                    acc[d][e2] += a[d] * b[e2];
        }
    }
#pragma unroll
    for (int d = 0; d < 4; ++d)
#pragma unroll
        for (int e2 = 0; e2 < 2; ++e2) {
            const int i = ti * 4 + d;
            const int j = jbase + tj * 2 + e2;
            atomicAdd(&O[(size_t)i * HDIM + j], acc[d][e2]);
        }
}

__global__ __launch_bounds__(256) void k_bias_act(
    float* __restrict__ Ak, float* __restrict__ Av,
    const float* __restrict__ bias, int relu)
{
    const int e = blockIdx.x * 256 + threadIdx.x;
    const int j = e & 2047;
    const float b = bias[j];
    float vk = Ak[e] + b;
    float vv = Av[e] + b;
    if (relu) { vk = fmaxf(vk, 0.f); vv = fmaxf(vv, 0.f); }
    Ak[e] = vk;
    Av[e] = vv;
}

__global__ __launch_bounds__(256) void k_out(
    const float* __restrict__ K, const float* __restrict__ V,
    const float* __restrict__ imp, const int* __restrict__ idx,
    const float* __restrict__ tck, const float* __restrict__ tcv,
    float* __restrict__ ok, float* __restrict__ ov)
{
    const size_t total = (size_t)NROWS * (HDIM / 4);
    for (size_t e = (size_t)blockIdx.x * 256 + threadIdx.x; e < total;
         e += (size_t)gridDim.x * 256) {
        const int r = (int)(e >> 9);
        const int q = (int)(e & 511);
        const bool pass = imp[r] > 0.1f;
        const int c = idx[r];
        const float4* sk = pass ? (const float4*)&K[(size_t)r * HDIM]
                                : (const float4*)&tck[(size_t)c * HDIM];
        const float4* sv = pass ? (const float4*)&V[(size_t)r * HDIM]
                                : (const float4*)&tcv[(size_t)c * HDIM];
        ((float4*)ok)[e] = sk[q];
        ((float4*)ov)[e] = sv[q];
    }
}

extern "C" void kernel_launch(void* const* d_in, const int* in_sizes, int n_in,
                              void* d_out, int out_size, void* d_ws,
                              size_t ws_size, hipStream_t stream)
{
    (void)in_sizes; (void)n_in; (void)out_size; (void)ws_size;
    const float* keys   = (const float*)d_in[0];
    const float* values = (const float*)d_in[1];
    const float* imp    = (const float*)d_in[2];
    const float* cw1    = (const float*)d_in[3];
    const float* cb1    = (const float*)d_in[4];
    const float* cw2    = (const float*)d_in[5];
    const float* cb2    = (const float*)d_in[6];
    const float* tw1    = (const float*)d_in[7];
    const float* tb1    = (const float*)d_in[8];
    const float* tw2    = (const float*)d_in[9];
    const float* tb2    = (const float*)d_in[10];
    const float* nk     = (const float*)d_in[11];
    const float* nv     = (const float*)d_in[12];

    char* ws = (char*)d_ws;
    int*   idx    = (int*)ws;
    float* counts = (float*)(ws + (64 << 10));
    float* kcent  = (float*)(ws + (128 << 10));
    float* vcent  = (float*)(ws + (384 << 10));
    float* hk     = (float*)(ws + (640 << 10));
    float* hv     = (float*)(ws + (896 << 10));
    float* tck    = (float*)(ws + (1152 << 10));
    float* tcv    = (float*)(ws + (1408 << 10));

    const size_t MB = (size_t)1 << 20;
    char* ob = (char*)d_out;
    short* kh   = (short*)(ob);
    short* hidH = (short*)(ob + 128 * MB);
    short* w1h  = (short*)(ob + 192 * MB);
    short* w2h  = (short*)(ob + 200 * MB);
    float* scoresAll = (float*)(ob + 201 * MB);
    char*  sb = ob + 204 * MB;
    int*   rcnt    = (int*)(sb);
    int*   rrows   = (int*)(sb + 1024);
    float* scoresR = (float*)(sb + (256 << 10));
    float* partK   = (float*)(ob + 208 * MB);
    float* partV   = (float*)(ob + 224 * MB);
    float* ok = (float*)d_out;
    float* ov = ok + (size_t)NROWS * HDIM;

    // zero atomic targets: counts + hk/hv/tck/tcv (+ kcent/vcent harmless)
    hipMemsetAsync(ws + (64 << 10), 0, (1664 - 64) << 10, stream);
    hipMemsetAsync(sb, 0, (256 << 10) + 2 * MB, stream);

    k_split_h<<<2048, 256, 0, stream>>>(keys, kh, NROWS * HDIM / 8);
    k_split_h<<<256, 256, 0, stream>>>(cw1, w1h, HHALF * HDIM / 8);
    k_split_h<<<16, 256, 0, stream>>>(cw2, w2h, NC * HHALF / 8);
    k_gemm1<<<1024, 256, 0, stream>>>(kh, w1h, cb1, hidH);
    k_gemm2<<<NROWS / 64, 256, 0, stream>>>(hidH, w2h, scoresAll);
    k_argmax<<<NROWS / 256, 256, 0, stream>>>(scoresAll, cb2, idx, rcnt, rrows, counts);
    k_refine_gemm<<<256, 256, 0, stream>>>(keys, cw1, cb1, cw2, rcnt, rrows, scoresR);
    k_refine_fix<<<NROWS / 256, 256, 0, stream>>>(rcnt, rrows, scoresR, cb2, idx, counts);
    k_psum<<<dim3(64, 8, 2), 256, 0, stream>>>(keys, values, idx, partK, partV);
    k_reduce<<<NC * HDIM / 256, 256, 0, stream>>>(partK, partV, kcent, vcent);
    k_final1<<<(NC * HDIM) / 256, 256, 0, stream>>>(kcent, vcent, counts);
    k_final2<<<(NC * HDIM) / 256, 256, 0, stream>>>(kcent, vcent, counts, nk, nv);
    k_mlp_sk<<<dim3(32, 2, 4), 256, 0, stream>>>(kcent, vcent, tw1, hk, hv);
    k_bias_act<<<256, 256, 0, stream>>>(hk, hv, tb1, 1);
    k_mlp_sk<<<dim3(32, 2, 4), 256, 0, stream>>>(hk, hv, tw2, tck, tcv);
    k_bias_act<<<256, 256, 0, stream>>>(tck, tcv, tb2, 0);
    k_out<<<2048, 256, 0, stream>>>(keys, values, imp, idx, tck, tcv, ok, ov);
}

// Round 10
// 477.359 us; speedup vs baseline: 1.5930x; 1.0227x over previous
//
#include <hip/hip_runtime.h>
#include <hip/hip_bf16.h>

#define NROWS 16384
#define HDIM  2048
#define HHALF 1024
#define NC    32
#define REFINE_TH 0.012f
#define REFINE_CAP 16384

typedef __attribute__((ext_vector_type(8)))  short  short8;
typedef __attribute__((ext_vector_type(16))) float  f32x16;

typedef __attribute__((address_space(3))) void lds_void;
typedef const __attribute__((address_space(1))) void gbl_void;

static __device__ __forceinline__ short f2h(float f) {
    _Float16 h = (_Float16)f;
    return *(short*)&h;
}
static __device__ __forceinline__ void gload16(const void* g, void* l) {
    __builtin_amdgcn_global_load_lds((gbl_void*)g, (lds_void*)l, 16, 0, 0);
}

// ---------------------------------------------------------------------------
// ws: [0,64K) idx | [64K,+128) counts | [128K,384K) kcent | [384K,640K) vcent
// [640K,896K) hk | [896K,1152K) hv | [1152K,1408K) tck | [1408K,1664K) tcv
//
// d_out (256MiB) = scratch until k_out overwrites it:
// [0,64M) kh (fp16 keys) | [128M,144M) scoresPart fp32[8][16384][32] |
// [192M,196M) w1h | [200M,+64K) w2h |
// [204M: +0 rcnt, +1K rrows[16384], +256K scoresR[16384*32] (2MB)]
// [208M,224M) partK fp32[64][32][2048] | [224M,240M) partV
// All consumed before k_out runs.
// ---------------------------------------------------------------------------

// fp32 -> fp16, 8 elems/thread, grid-stride
__global__ __launch_bounds__(256) void k_split_h(const float* __restrict__ src,
                                                 short* __restrict__ dst, int n8)
{
    const int stride = gridDim.x * 256;
    for (int i = blockIdx.x * 256 + threadIdx.x; i < n8; i += stride) {
        float4 a = ((const float4*)src)[(size_t)i * 2];
        float4 b = ((const float4*)src)[(size_t)i * 2 + 1];
        float f[8] = {a.x, a.y, a.z, a.w, b.x, b.y, b.z, b.w};
        short h[8];
#pragma unroll
        for (int e = 0; e < 8; ++e) h[e] = f2h(f[e]);
        *(short8*)&dst[(size_t)i * 8] = *(short8*)h;
    }
}

// GEMM1 + fused layer-2: per block, hidden tile 128x128 stays on-chip.
// Main loop: 128x128 tile, BK=64, single fp16 MFMA, swizzled LDS.
// Epilogue: hidden -> LDS (reusing A/B staging space, gemm2-style swizzle),
// 8 MFMAs/wave against the w2 slice -> partial score plane for this jb.
__global__ __launch_bounds__(256) void k_gemm1(
    const short* __restrict__ kh, const short* __restrict__ w1h,
    const float* __restrict__ cb1, const short* __restrict__ w2h,
    float* __restrict__ scoresPart)
{
    __shared__ alignas(16) short smem[20480];  // 40 KB
    short* Ah = smem;           // [128][64]  16 KB (main loop)
    short* Bh = smem + 8192;    // [128][64]  16 KB (main loop)
    short* Hs = smem;           // [128][128] 32 KB (epilogue, reuses Ah+Bh)
    short* W2 = smem + 16384;   // [32][128]   8 KB (epilogue)

    const int tid = threadIdx.x;
    const int w = tid >> 6, lane = tid & 63;
    const int wr = w & 1, wc = w >> 1;
    const int l31 = lane & 31, lq5 = lane >> 5;

    const int d = blockIdx.x;
    const int xcd = d & 7, t = d >> 3;
    const int jb = t >> 4;
    const int rb = ((t & 15) << 3) | xcd;
    const int row0 = rb * 128, col0 = jb * 128;

    const int s_swz = (lane & 7) ^ (lane >> 3);

    f32x16 acc[2][2] = {};

    for (int kt = 0; kt < 32; ++kt) {
        const int k0 = kt * 64;
        __syncthreads();
#pragma unroll
        for (int q = 0; q < 4; ++q) {
            const int c = w * 4 + q;
            const int r = c * 8 + (lane >> 3);
            const size_t ga = ((size_t)(row0 + r) * HDIM + k0) * 2 + s_swz * 16;
            const size_t gb = ((size_t)(col0 + r) * HDIM + k0) * 2 + s_swz * 16;
            gload16((const char*)kh + ga, &Ah[c * 512]);
            gload16((const char*)w1h + gb, &Bh[c * 512]);
        }
        __syncthreads();
#pragma unroll
        for (int ks = 0; ks < 4; ++ks) {
            const int sw = (((ks * 2 + lq5) ^ (l31 & 7)) << 3);
            short8 aH[2], bH[2];
#pragma unroll
            for (int m = 0; m < 2; ++m)
                aH[m] = *(const short8*)&Ah[(wr * 64 + m * 32 + l31) * 64 + sw];
#pragma unroll
            for (int n = 0; n < 2; ++n)
                bH[n] = *(const short8*)&Bh[(wc * 64 + n * 32 + l31) * 64 + sw];
#pragma unroll
            for (int m = 0; m < 2; ++m)
#pragma unroll
                for (int n = 0; n < 2; ++n)
                    acc[m][n] = __builtin_amdgcn_mfma_f32_32x32x16_f16(aH[m], bH[n], acc[m][n], 0, 0, 0);
        }
    }

    // ---- epilogue: hidden -> LDS (swizzled), stage w2 slice ----
    __syncthreads();  // all waves done reading Ah/Bh
#pragma unroll
    for (int q = 0; q < 2; ++q) {                 // w2 slice: 8 x 1KB chunks
        const int ch = w * 2 + q;
        const int r  = ch * 4 + (lane >> 4);      // w2 row 0..31
        const int s  = lane & 15;
        const size_t g = (size_t)r * (HHALF * 2) + (size_t)col0 * 2
                       + (size_t)((s ^ (r & 15)) * 16);
        gload16((const char*)w2h + g, &W2[ch * 512]);
    }
#pragma unroll
    for (int n = 0; n < 2; ++n) {
        const int col = wc * 64 + n * 32 + l31;   // local 0..127
        const float bias = cb1[col0 + col];
#pragma unroll
        for (int m = 0; m < 2; ++m) {
#pragma unroll
            for (int r = 0; r < 16; ++r) {
                const int row = wr * 64 + m * 32 + (r & 3) + 8 * (r >> 2) + 4 * lq5;
                const float h = fmaxf(acc[m][n][r] + bias, 0.f);
                Hs[row * 128 + ((((col >> 3) ^ (row & 15)) << 3) + (col & 7))] = f2h(h);
            }
        }
    }
    __syncthreads();

    // ---- layer-2: wave w computes rows w*32..+32 x 32 centroids, k=128 ----
    f32x16 sacc = {};
#pragma unroll
    for (int ks = 0; ks < 8; ++ks) {
        const int kc = ks * 2 + lq5;              // 16B chunk 0..15
        const int rowA = w * 32 + l31;
        short8 aH = *(const short8*)&Hs[rowA * 128 + ((kc ^ (rowA & 15)) << 3)];
        short8 bH = *(const short8*)&W2[l31 * 128 + ((kc ^ (l31 & 15)) << 3)];
        sacc = __builtin_amdgcn_mfma_f32_32x32x16_f16(aH, bH, sacc, 0, 0, 0);
    }
#pragma unroll
    for (int r = 0; r < 16; ++r) {
        const int row = row0 + w * 32 + (r & 3) + 8 * (r >> 2) + 4 * lq5;
        scoresPart[((size_t)jb * NROWS + row) * NC + l31] = sacc[r];
    }
}

// argmax over summed partial planes + low-margin flagging + counts histogram
__global__ __launch_bounds__(256) void k_argmax(
    const float* __restrict__ sp, const float* __restrict__ cb2,
    int* __restrict__ idx, int* __restrict__ rcnt, int* __restrict__ rrows,
    float* __restrict__ counts)
{
    __shared__ int hist[NC];
    if (threadIdx.x < NC) hist[threadIdx.x] = 0;
    __syncthreads();
    const int row = blockIdx.x * 256 + threadIdx.x;
    float s[NC];
#pragma unroll
    for (int c = 0; c < NC; ++c) s[c] = 0.f;
#pragma unroll
    for (int p = 0; p < 8; ++p) {
        const float4* v4 = (const float4*)&sp[((size_t)p * NROWS + row) * NC];
#pragma unroll
        for (int q = 0; q < 8; ++q) {
            float4 v = v4[q];
            s[q * 4 + 0] += v.x; s[q * 4 + 1] += v.y;
            s[q * 4 + 2] += v.z; s[q * 4 + 3] += v.w;
        }
    }
    float best = -3.4e38f, second = -3.4e38f;
    int bi = 0;
#pragma unroll
    for (int c = 0; c < NC; ++c) {
        const float v = s[c] + cb2[c];
        if (v > best) { second = best; best = v; bi = c; }
        else if (v > second) second = v;
    }
    idx[row] = bi;
    atomicAdd(&hist[bi], 1);
    if (best - second < REFINE_TH) {
        int slot = atomicAdd(rcnt, 1);
        if (slot < REFINE_CAP) rrows[slot] = row;
    }
    __syncthreads();
    if (threadIdx.x < NC)
        atomicAdd(&counts[threadIdx.x], (float)hist[threadIdx.x]);
}

// exact fp32 recompute of scores for flagged rows
__global__ __launch_bounds__(256) void k_refine_gemm(
    const float* __restrict__ K, const float* __restrict__ cw1,
    const float* __restrict__ cb1, const float* __restrict__ cw2,
    const int* __restrict__ rcnt, const int* __restrict__ rrows,
    float* __restrict__ scoresR)
{
    const int cnt = min(*rcnt, REFINE_CAP);
    if (cnt == 0) return;
    const int units = ((cnt + 63) >> 6) * 16;
    __shared__ float KsT[64][68];
    __shared__ float WsT[64][68];
    __shared__ float Hs2[64][68];
    __shared__ float W2f[NC][68];

    const int tid = threadIdx.x;
    const int ti = tid & 15, tj = tid >> 4;
    const int si = tid & 63, sc0 = (tid >> 6) * 8;

    for (int u = blockIdx.x; u < units; u += gridDim.x) {
        const int rc = u >> 4, jt = u & 15, j0 = jt * 64;
        const int M = min(cnt - rc * 64, 64);

        float hacc[4][4];
#pragma unroll
        for (int a = 0; a < 4; ++a)
#pragma unroll
            for (int b = 0; b < 4; ++b) hacc[a][b] = 0.f;

        for (int kt = 0; kt < 32; ++kt) {
            const int k0 = kt * 64;
            __syncthreads();
            {
                const int r  = tid >> 2;
                const int kb = (tid & 3) * 16;
                const int grow = rrows[rc * 64 + min(r, M - 1)];
#pragma unroll
                for (int q = 0; q < 4; ++q) {
                    float4 v = *(const float4*)&K[(size_t)grow * HDIM + k0 + kb + q * 4];
                    KsT[kb + q * 4 + 0][r] = v.x; KsT[kb + q * 4 + 1][r] = v.y;
                    KsT[kb + q * 4 + 2][r] = v.z; KsT[kb + q * 4 + 3][r] = v.w;
                }
                const int j = tid >> 2;
#pragma unroll
                for (int q = 0; q < 4; ++q) {
                    float4 v = *(const float4*)&cw1[(size_t)(j0 + j) * HDIM + k0 + kb + q * 4];
                    WsT[kb + q * 4 + 0][j] = v.x; WsT[kb + q * 4 + 1][j] = v.y;
                    WsT[kb + q * 4 + 2][j] = v.z; WsT[kb + q * 4 + 3][j] = v.w;
                }
            }
            __syncthreads();
#pragma unroll 4
            for (int k = 0; k < 64; ++k) {
                float4 a = *(float4*)&KsT[k][ti * 4];
                float4 b = *(float4*)&WsT[k][tj * 4];
                float av[4] = {a.x, a.y, a.z, a.w};
                float bv[4] = {b.x, b.y, b.z, b.w};
#pragma unroll
                for (int di = 0; di < 4; ++di)
#pragma unroll
                    for (int dj = 0; dj < 4; ++dj)
                        hacc[di][dj] += av[di] * bv[dj];
            }
        }
        __syncthreads();
#pragma unroll
        for (int di = 0; di < 4; ++di)
#pragma unroll
            for (int dj = 0; dj < 4; ++dj) {
                float h = hacc[di][dj] + cb1[j0 + tj * 4 + dj];
                Hs2[ti * 4 + di][tj * 4 + dj] = fmaxf(h, 0.f);
            }
        {
            const int c  = tid >> 3;
            const int jq = (tid & 7) * 8;
            *(float4*)&W2f[c][jq]     = *(const float4*)&cw2[(size_t)c * HHALF + j0 + jq];
            *(float4*)&W2f[c][jq + 4] = *(const float4*)&cw2[(size_t)c * HHALF + j0 + jq + 4];
        }
        __syncthreads();
        float sacc[8];
#pragma unroll
        for (int q = 0; q < 8; ++q) sacc[q] = 0.f;
        for (int j = 0; j < 64; ++j) {
            float h = Hs2[si][j];
#pragma unroll
            for (int q = 0; q < 8; ++q) sacc[q] += h * W2f[sc0 + q][j];
        }
        if (si < M) {
#pragma unroll
            for (int q = 0; q < 8; ++q)
                atomicAdd(&scoresR[(size_t)(rc * 64 + si) * NC + sc0 + q], sacc[q]);
        }
        __syncthreads();
    }
}

__global__ __launch_bounds__(256) void k_refine_fix(
    const int* __restrict__ rcnt, const int* __restrict__ rrows,
    const float* __restrict__ scoresR, const float* __restrict__ cb2,
    int* __restrict__ idx, float* __restrict__ counts)
{
    const int cnt = min(*rcnt, REFINE_CAP);
    const int t = blockIdx.x * 256 + threadIdx.x;
    if (t >= cnt) return;
    float best = -3.4e38f;
    int bi = 0;
    for (int c = 0; c < NC; ++c) {
        float v = scoresR[(size_t)t * NC + c] + cb2[c];
        if (v > best) { best = v; bi = c; }
    }
    const int row = rrows[t];
    const int old = idx[row];
    if (old != bi) {
        idx[row] = bi;
        atomicAdd(&counts[old], -1.f);
        atomicAdd(&counts[bi], 1.f);
    }
}

// Phase A of segment-sum: exclusive column ownership -> no atomics/barriers.
__global__ __launch_bounds__(256) void k_psum(
    const float* __restrict__ K, const float* __restrict__ V,
    const int* __restrict__ idx, float* __restrict__ partK,
    float* __restrict__ partV)
{
    __shared__ float ps[NC][256];
    const int rb = blockIdx.x;
    const int cb = blockIdx.y;
    const float* X = blockIdx.z ? V : K;
    float* P       = blockIdx.z ? partV : partK;
    const int tid = threadIdx.x;
    const int col = cb * 256 + tid;

#pragma unroll
    for (int c = 0; c < NC; ++c) ps[c][tid] = 0.f;

    const int row0 = rb * 256;
#pragma unroll 4
    for (int r = 0; r < 256; ++r) {
        const int row = row0 + r;
        const int c = idx[row];
        const float v = X[(size_t)row * HDIM + col];
        ps[c][tid] += v;
    }

#pragma unroll
    for (int c = 0; c < NC; ++c)
        P[((size_t)rb * NC + c) * HDIM + col] = ps[c][tid];
}

// Phase B fused with finalize: reduce 64 partials, divide by counts,
// reseed empty centroids from the most-populated one (+0.1*noise).
__global__ __launch_bounds__(256) void k_reduce_final(
    const float* __restrict__ partK, const float* __restrict__ partV,
    const float* __restrict__ counts, const float* __restrict__ nk,
    const float* __restrict__ nv, float* __restrict__ kcent,
    float* __restrict__ vcent)
{
    const int e = blockIdx.x * 256 + threadIdx.x;  // 65536
    const int c = e >> 11, h = e & 2047;
    const float cc = counts[c];
    int lookup = c;
    if (cc == 0.f) {
        int src = 0;
        float best = counts[0];
        for (int j = 1; j < NC; ++j) {
            float v = counts[j];
            if (v > best) { best = v; src = j; }
        }
        lookup = src;
    }
    float sk = 0.f, sv = 0.f;
    const size_t base = (size_t)lookup * HDIM + h;
#pragma unroll 8
    for (int rb = 0; rb < 64; ++rb) {
        sk += partK[(size_t)rb * (NC * HDIM) + base];
        sv += partV[(size_t)rb * (NC * HDIM) + base];
    }
    const float denom = fmaxf(counts[lookup], 1.f);
    float mk = sk / denom, mv = sv / denom;
    if (cc == 0.f) { mk += 0.1f * nk[e]; mv += 0.1f * nv[e]; }
    kcent[e] = mk;
    vcent[e] = mv;
}

// split-K MLP layer over the 32 centroids: grid (jt=32, kv=2, ks=4).
__global__ __launch_bounds__(256) void k_mlp_sk(
    const float* __restrict__ Xk, const float* __restrict__ Xv,
    const float* __restrict__ W, float* __restrict__ Ok,
    float* __restrict__ Ov)
{
    __shared__ float Xs[32][65];
    __shared__ float Wt[64][65];
    const float* X = blockIdx.y ? Xv : Xk;
    float* O       = blockIdx.y ? Ov : Ok;
    const int tid   = threadIdx.x;
    const int jbase = blockIdx.x * 64;
    const int kbase = blockIdx.z * 512;
    const int ti = tid & 7;
    const int tj = tid >> 3;
    float acc[4][2];
#pragma unroll
    for (int a = 0; a < 4; ++a) { acc[a][0] = 0.f; acc[a][1] = 0.f; }

    for (int kt = 0; kt < 8; ++kt) {
        const int k0 = kbase + kt * 64;
        __syncthreads();
        {
            const int f4 = tid & 15;
            const int r  = tid >> 4;
#pragma unroll
            for (int rr = 0; rr < 2; ++rr) {
                const int row = r + rr * 16;
                float4 xv = *(const float4*)&X[(size_t)row * HDIM + k0 + f4 * 4];
                Xs[row][f4 * 4 + 0] = xv.x; Xs[row][f4 * 4 + 1] = xv.y;
                Xs[row][f4 * 4 + 2] = xv.z; Xs[row][f4 * 4 + 3] = xv.w;
            }
#pragma unroll
            for (int rr = 0; rr < 4; ++rr) {
                const int row = r + rr * 16;
                float4 wv = *(const float4*)&W[(size_t)(jbase + row) * HDIM + k0 + f4 * 4];
                Wt[row][f4 * 4 + 0] = wv.x; Wt[row][f4 * 4 + 1] = wv.y;
                Wt[row][f4 * 4 + 2] = wv.z; Wt[row][f4 * 4 + 3] = wv.w;
            }
        }
        __syncthreads();
#pragma unroll 8
        for (int k = 0; k < 64; ++k) {
            float a[4], b[2];
#pragma unroll
            for (int d = 0; d < 4; ++d) a[d] = Xs[ti * 4 + d][k];
#pragma unroll
            for (int d = 0; d < 2; ++d) b[d] = Wt[tj * 2 + d][k];
#pragma unroll
            for (int d = 0; d < 4; ++d)
#pragma unroll
                for (int e2 = 0; e2 < 2; ++e2)
                    acc[d][e2] += a[d] * b[e2];
        }
    }
#pragma unroll
    for (int d = 0; d < 4; ++d)
#pragma unroll
        for (int e2 = 0; e2 < 2; ++e2) {
            const int i = ti * 4 + d;
            const int j = jbase + tj * 2 + e2;
            atomicAdd(&O[(size_t)i * HDIM + j], acc[d][e2]);
        }
}

__global__ __launch_bounds__(256) void k_bias_act(
    float* __restrict__ Ak, float* __restrict__ Av,
    const float* __restrict__ bias, int relu)
{
    const int e = blockIdx.x * 256 + threadIdx.x;
    const int j = e & 2047;
    const float b = bias[j];
    float vk = Ak[e] + b;
    float vv = Av[e] + b;
    if (relu) { vk = fmaxf(vk, 0.f); vv = fmaxf(vv, 0.f); }
    Ak[e] = vk;
    Av[e] = vv;
}

// output assembly: one wave owns a whole row -> imp/idx loaded once,
// wave-uniform branch, pure 16B/lane streams.
__global__ __launch_bounds__(256) void k_out(
    const float* __restrict__ K, const float* __restrict__ V,
    const float* __restrict__ imp, const int* __restrict__ idx,
    const float* __restrict__ tck, const float* __restrict__ tcv,
    float* __restrict__ ok, float* __restrict__ ov)
{
    const int w = threadIdx.x >> 6, lane = threadIdx.x & 63;
    const int wv = blockIdx.x * 4 + w;   // 0..8191
#pragma unroll
    for (int rr = 0; rr < 2; ++rr) {
        const int row = wv * 2 + rr;
        const bool pass = imp[row] > 0.1f;
        const int c = idx[row];
        const float4* sk = pass ? (const float4*)&K[(size_t)row * HDIM]
                                : (const float4*)&tck[(size_t)c * HDIM];
        const float4* sv = pass ? (const float4*)&V[(size_t)row * HDIM]
                                : (const float4*)&tcv[(size_t)c * HDIM];
        float4* dk = (float4*)&ok[(size_t)row * HDIM];
        float4* dv = (float4*)&ov[(size_t)row * HDIM];
#pragma unroll
        for (int it = 0; it < 8; ++it) {
            dk[it * 64 + lane] = sk[it * 64 + lane];
            dv[it * 64 + lane] = sv[it * 64 + lane];
        }
    }
}

extern "C" void kernel_launch(void* const* d_in, const int* in_sizes, int n_in,
                              void* d_out, int out_size, void* d_ws,
                              size_t ws_size, hipStream_t stream)
{
    (void)in_sizes; (void)n_in; (void)out_size; (void)ws_size;
    const float* keys   = (const float*)d_in[0];
    const float* values = (const float*)d_in[1];
    const float* imp    = (const float*)d_in[2];
    const float* cw1    = (const float*)d_in[3];
    const float* cb1    = (const float*)d_in[4];
    const float* cw2    = (const float*)d_in[5];
    const float* cb2    = (const float*)d_in[6];
    const float* tw1    = (const float*)d_in[7];
    const float* tb1    = (const float*)d_in[8];
    const float* tw2    = (const float*)d_in[9];
    const float* tb2    = (const float*)d_in[10];
    const float* nk     = (const float*)d_in[11];
    const float* nv     = (const float*)d_in[12];

    char* ws = (char*)d_ws;
    int*   idx    = (int*)ws;
    float* counts = (float*)(ws + (64 << 10));
    float* kcent  = (float*)(ws + (128 << 10));
    float* vcent  = (float*)(ws + (384 << 10));
    float* hk     = (float*)(ws + (640 << 10));
    float* hv     = (float*)(ws + (896 << 10));
    float* tck    = (float*)(ws + (1152 << 10));
    float* tcv    = (float*)(ws + (1408 << 10));

    const size_t MB = (size_t)1 << 20;
    char* ob = (char*)d_out;
    short* kh   = (short*)(ob);
    float* scoresPart = (float*)(ob + 128 * MB);
    short* w1h  = (short*)(ob + 192 * MB);
    short* w2h  = (short*)(ob + 200 * MB);
    char*  sb = ob + 204 * MB;
    int*   rcnt    = (int*)(sb);
    int*   rrows   = (int*)(sb + 1024);
    float* scoresR = (float*)(sb + (256 << 10));
    float* partK   = (float*)(ob + 208 * MB);
    float* partV   = (float*)(ob + 224 * MB);
    float* ok = (float*)d_out;
    float* ov = ok + (size_t)NROWS * HDIM;

    // zero atomic targets: counts (128B), hk/hv/tck/tcv (1MB), rcnt+scoresR
    hipMemsetAsync(ws + (64 << 10), 0, 128, stream);
    hipMemsetAsync(ws + (640 << 10), 0, 1 * MB, stream);
    hipMemsetAsync(sb, 0, (256 << 10) + 2 * MB, stream);

    k_split_h<<<2048, 256, 0, stream>>>(keys, kh, NROWS * HDIM / 8);
    k_split_h<<<256, 256, 0, stream>>>(cw1, w1h, HHALF * HDIM / 8);
    k_split_h<<<16, 256, 0, stream>>>(cw2, w2h, NC * HHALF / 8);
    k_gemm1<<<1024, 256, 0, stream>>>(kh, w1h, cb1, w2h, scoresPart);
    k_argmax<<<NROWS / 256, 256, 0, stream>>>(scoresPart, cb2, idx, rcnt, rrows, counts);
    k_refine_gemm<<<256, 256, 0, stream>>>(keys, cw1, cb1, cw2, rcnt, rrows, scoresR);
    k_refine_fix<<<NROWS / 256, 256, 0, stream>>>(rcnt, rrows, scoresR, cb2, idx, counts);
    k_psum<<<dim3(64, 8, 2), 256, 0, stream>>>(keys, values, idx, partK, partV);
    k_reduce_final<<<NC * HDIM / 256, 256, 0, stream>>>(partK, partV, counts,
                                                        nk, nv, kcent, vcent);
    k_mlp_sk<<<dim3(32, 2, 4), 256, 0, stream>>>(kcent, vcent, tw1, hk, hv);
    k_bias_act<<<256, 256, 0, stream>>>(hk, hv, tb1, 1);
    k_mlp_sk<<<dim3(32, 2, 4), 256, 0, stream>>>(hk, hv, tw2, tck, tcv);
    k_bias_act<<<256, 256, 0, stream>>>(tck, tcv, tb2, 0);
    k_out<<<2048, 256, 0, stream>>>(keys, values, imp, idx, tck, tcv, ok, ov);
}